// Round 9
// baseline (528.863 us; speedup 1.0000x reference)
//
#include <hip/hip_runtime.h>

#define F 128
#define CLSN 40
#define NFINE_MAX 256
#define PCAP 10240
#define TILE 4096
#define STAGE_CAP 10240

typedef __attribute__((ext_vector_type(8))) short short8v;
typedef __attribute__((ext_vector_type(4))) float float4v;

static __device__ inline ushort f2bf(float f) {
  uint u = __float_as_uint(f);
  uint r = (u + 0x7FFFu + ((u >> 16) & 1u)) >> 16;
  return (ushort)r;
}
static __device__ inline float bfLo(uint u) { return __uint_as_float(u << 16); }
static __device__ inline float bfHi(uint u) { return __uint_as_float(u & 0xFFFF0000u); }

// ---------------- casts / packing ----------------
__global__ __launch_bounds__(256) void k_cast(const float* __restrict__ in,
                                              ushort* __restrict__ outb, int nelem4) {
  int i = blockIdx.x * 256 + threadIdx.x;
  if (i < nelem4) {
    float4 v = reinterpret_cast<const float4*>(in)[i];
    ushort4 o;
    o.x = f2bf(v.x); o.y = f2bf(v.y); o.z = f2bf(v.z); o.w = f2bf(v.w);
    reinterpret_cast<ushort4*>(outb)[i] = o;
  }
}

// pack [Wl1;Wr1] (256x128) into MFMA B-frag order: Wp[((ks*8+f)*64+lane)*8+j]
__global__ __launch_bounds__(256) void k_pack_w1(const float* __restrict__ Wl,
                                                 const float* __restrict__ Wr,
                                                 ushort* __restrict__ Wp) {
  int t = blockIdx.x * 256 + threadIdx.x;
  if (t >= 4096) return;
  int lane = t & 63, f = (t >> 6) & 7, ks = t >> 9;
  int col = f * 16 + (lane & 15);
  int k0 = ks * 32 + (lane >> 4) * 8;
#pragma unroll
  for (int j = 0; j < 8; ++j) {
    int k = k0 + j;
    float w = (k < 128) ? Wl[k * 128 + col] : Wr[(k - 128) * 128 + col];
    Wp[t * 8 + j] = f2bf(w);
  }
}

// pack Wl2 and Wr2 (each 128x40, pad cols to 48) as K=128 frags: 4ks x 3f
__global__ __launch_bounds__(256) void k_pack_w2pair(const float* __restrict__ Wl,
                                                     const float* __restrict__ Wr,
                                                     ushort* __restrict__ Wpl,
                                                     ushort* __restrict__ Wpr) {
  int t = blockIdx.x * 256 + threadIdx.x;
  if (t >= 1536) return;
  const float* W = (t < 768) ? Wl : Wr;
  ushort* Wp = (t < 768) ? Wpl : Wpr;
  int tt = (t < 768) ? t : t - 768;
  int lane = tt & 63, rem = tt >> 6;
  int f = rem % 3, ks = rem / 3;
  int col = f * 16 + (lane & 15);
  int k0 = ks * 32 + (lane >> 4) * 8;
#pragma unroll
  for (int j = 0; j < 8; ++j) {
    int k = k0 + j;
    float w = (col < CLSN) ? W[k * CLSN + col] : 0.f;
    Wp[tt * 8 + j] = f2bf(w);
  }
}

// ---------------- one-pass tiled radix partition into fine buckets ----------------
__global__ void k_init_fcur(int* __restrict__ fcur, int nfine) {
  int i = blockIdx.x * 256 + threadIdx.x;
  if (i < nfine) fcur[i] = i * PCAP;
}

__global__ __launch_bounds__(256) void k_partition(const int* __restrict__ src,
                                                   const int* __restrict__ dst,
                                                   int* __restrict__ fcur,
                                                   uint* __restrict__ pairs, int E) {
  __shared__ int hh[NFINE_MAX];
  __shared__ int bb[NFINE_MAX];
  __shared__ unsigned char ebkt[TILE];
  __shared__ ushort dlow[TILE];
  const int tid = threadIdx.x;
  const int tile0 = blockIdx.x * TILE;
  const int lim = min(TILE, E - tile0);
  for (int i = tid; i < NFINE_MAX; i += 256) hh[i] = 0;
  __syncthreads();
  for (int i = tid; i < lim; i += 256) {
    int d = dst[tile0 + i];
    int b = d >> 9;
    ebkt[i] = (unsigned char)b;
    dlow[i] = (ushort)(d & 511);
    atomicAdd(&hh[b], 1);
  }
  __syncthreads();
  for (int i = tid; i < NFINE_MAX; i += 256) {
    int c = hh[i];
    bb[i] = c ? atomicAdd(&fcur[i], c) : 0;
    hh[i] = 0;  // reuse as local cursor
  }
  __syncthreads();
  for (int i = tid; i < lim; i += 256) {
    int b = ebkt[i];
    int r = atomicAdd(&hh[b], 1);
    uint p = (uint)src[tile0 + i] | ((uint)dlow[i] << 17);
    pairs[bb[b] + r] = p;
  }
}

__global__ __launch_bounds__(256) void k_scan_fine(const int* __restrict__ fcur,
                                                   int* __restrict__ fbase,
                                                   int nfine, int E) {
  __shared__ int s[256];
  int tid = threadIdx.x;
  int v = (tid < nfine) ? (fcur[tid] - tid * PCAP) : 0;
  s[tid] = v;
  __syncthreads();
  for (int d = 1; d < 256; d <<= 1) {
    int u = (tid >= d) ? s[tid - d] : 0;
    __syncthreads();
    s[tid] += u;
    __syncthreads();
  }
  if (tid < nfine) fbase[tid] = s[tid] - v;
  if (tid == 0) fbase[nfine] = E;
}

__global__ __launch_bounds__(256) void k_local_scatter(const uint* __restrict__ pairs,
                                                       const int* __restrict__ fcur,
                                                       const int* __restrict__ fbase,
                                                       int* __restrict__ offsets,
                                                       int* __restrict__ srcs,
                                                       int n, int E) {
  __shared__ int s_cnt[512];
  __shared__ int s_scan[512];
  __shared__ int s_stage[STAGE_CAP];
  const int b = blockIdx.x, tid = threadIdx.x;
  const int node0 = b << 9;
  const int pbase = b * PCAP;
  const int ebase = fbase[b];
  const int ecnt = fcur[b] - pbase;
  s_cnt[tid] = 0;
  s_cnt[tid + 256] = 0;
  __syncthreads();
  for (int i = tid; i < ecnt; i += 256) atomicAdd(&s_cnt[pairs[pbase + i] >> 17], 1);
  __syncthreads();
  s_scan[tid] = s_cnt[tid];
  s_scan[tid + 256] = s_cnt[tid + 256];
  __syncthreads();
  for (int d = 1; d < 512; d <<= 1) {
    int v0 = (tid >= d) ? s_scan[tid - d] : 0;
    int v1 = (tid + 256 >= d) ? s_scan[tid + 256 - d] : 0;
    __syncthreads();
    s_scan[tid] += v0;
    s_scan[tid + 256] += v1;
    __syncthreads();
  }
  int e0 = s_scan[tid] - s_cnt[tid];
  int e1 = s_scan[tid + 256] - s_cnt[tid + 256];
  if (node0 + tid < n) offsets[node0 + tid] = ebase + e0;
  if (node0 + tid + 256 < n) offsets[node0 + tid + 256] = ebase + e1;
  if (b == gridDim.x - 1 && tid == 0) offsets[n] = E;
  __syncthreads();
  s_cnt[tid] = e0;
  s_cnt[tid + 256] = e1;
  __syncthreads();
  for (int i = tid; i < ecnt; i += 256) {
    uint p = pairs[pbase + i];
    int v = (int)(p >> 17);
    int s = (int)(p & 0x1FFFFu);
    int pos = atomicAdd(&s_cnt[v], 1);
    if (pos < STAGE_CAP) s_stage[pos] = s;
    else srcs[ebase + pos] = s;
  }
  __syncthreads();
  int lim = min(ecnt, STAGE_CAP);
  for (int i = tid; i < lim; i += 256) srcs[ebase + i] = s_stage[i];
}

// ---------------- XCD-slice-local mean aggregation (row-major outputs) ----------------
// x: one wave per (node, slice); slice = blockIdx%8 (XCD round-robin); 8-lane group g
// handles edges k = g, g+8, ...; lane reads uint u of the node's 32B slice.
// Output mean row-major [n][128] bf16 (identical layout to round 7).
__global__ __launch_bounds__(256) void k_agg_x_s(const ushort* __restrict__ feat,
                                                 const int* __restrict__ offsets,
                                                 const int* __restrict__ srcs,
                                                 ushort* __restrict__ mean, int n) {
  const int bid = blockIdx.x;
  const int slice = bid & 7;
  const int w = threadIdx.x >> 6;
  const int lane = threadIdx.x & 63;
  const int node = (bid >> 3) * 4 + w;
  if (node >= n) return;
  const int g = lane >> 3;
  const int u = lane & 7;
  const uint* fp = reinterpret_cast<const uint*>(feat);
  const int beg = offsets[node];
  const int deg = offsets[node + 1] - beg;
  const int base = slice * 8 + u;
  float a0 = 0.f, a1 = 0.f;
  int k = g;
  for (; k + 24 < deg; k += 32) {
    int r0 = srcs[beg + k];
    int r1 = srcs[beg + k + 8];
    int r2 = srcs[beg + k + 16];
    int r3 = srcs[beg + k + 24];
    uint v0 = fp[(size_t)r0 * 64 + base];
    uint v1 = fp[(size_t)r1 * 64 + base];
    uint v2 = fp[(size_t)r2 * 64 + base];
    uint v3 = fp[(size_t)r3 * 64 + base];
    a0 += bfLo(v0) + bfLo(v1) + bfLo(v2) + bfLo(v3);
    a1 += bfHi(v0) + bfHi(v1) + bfHi(v2) + bfHi(v3);
  }
  for (; k < deg; k += 8) {
    uint v0 = fp[(size_t)srcs[beg + k] * 64 + base];
    a0 += bfLo(v0);
    a1 += bfHi(v0);
  }
  a0 += __shfl_xor(a0, 8);  a1 += __shfl_xor(a1, 8);
  a0 += __shfl_xor(a0, 16); a1 += __shfl_xor(a1, 16);
  a0 += __shfl_xor(a0, 32); a1 += __shfl_xor(a1, 32);
  if (g == 0) {
    float inv = deg > 0 ? 1.f / (float)deg : 0.f;
    uint o = (uint)f2bf(a0 * inv) | ((uint)f2bf(a1 * inv) << 16);
    reinterpret_cast<uint*>(mean)[(size_t)node * 64 + base] = o;
  }
}

// p: rows are 64 bf16 (32 uints) row-major; slice = blockIdx%4 (16 cols each,
// incl. zero-pad slice 3). Output m row-major [n][64] fp32 (round-7 layout).
__global__ __launch_bounds__(256) void k_agg_p_s(const ushort* __restrict__ p,
                                                 const int* __restrict__ offsets,
                                                 const int* __restrict__ srcs,
                                                 float* __restrict__ m, int n) {
  const int bid = blockIdx.x;
  const int slice = bid & 3;
  const int w = threadIdx.x >> 6;
  const int lane = threadIdx.x & 63;
  const int node = (bid >> 2) * 4 + w;
  if (node >= n) return;
  const int g = lane >> 3;
  const int u = lane & 7;
  const uint* pp = reinterpret_cast<const uint*>(p);
  const int beg = offsets[node];
  const int deg = offsets[node + 1] - beg;
  const int base = slice * 8 + u;
  float a0 = 0.f, a1 = 0.f;
  int k = g;
  for (; k + 24 < deg; k += 32) {
    int r0 = srcs[beg + k];
    int r1 = srcs[beg + k + 8];
    int r2 = srcs[beg + k + 16];
    int r3 = srcs[beg + k + 24];
    uint v0 = pp[(size_t)r0 * 32 + base];
    uint v1 = pp[(size_t)r1 * 32 + base];
    uint v2 = pp[(size_t)r2 * 32 + base];
    uint v3 = pp[(size_t)r3 * 32 + base];
    a0 += bfLo(v0) + bfLo(v1) + bfLo(v2) + bfLo(v3);
    a1 += bfHi(v0) + bfHi(v1) + bfHi(v2) + bfHi(v3);
  }
  for (; k < deg; k += 8) {
    uint v0 = pp[(size_t)srcs[beg + k] * 32 + base];
    a0 += bfLo(v0);
    a1 += bfHi(v0);
  }
  a0 += __shfl_xor(a0, 8);  a1 += __shfl_xor(a1, 8);
  a0 += __shfl_xor(a0, 16); a1 += __shfl_xor(a1, 16);
  a0 += __shfl_xor(a0, 32); a1 += __shfl_xor(a1, 32);
  if (g == 0) {
    float inv = deg > 0 ? 1.f / (float)deg : 0.f;
    reinterpret_cast<float2*>(m)[(size_t)node * 32 + base] =
        make_float2(a0 * inv, a1 * inv);
  }
}

// ---------------- layer1 MFMA GEMM: h = relu([mean|x]@Wp1 + b1), bf16 out ------------
// (byte-identical to round 7)
__global__ __launch_bounds__(256) void k_mfma1(const ushort* __restrict__ meanb,
                                               const ushort* __restrict__ rootb,
                                               const ushort* __restrict__ Wp,
                                               const float* __restrict__ b,
                                               ushort* __restrict__ h, int nrows) {
  __shared__ __align__(16) ushort As[64 * 256];  // 32KB, XOR-swizzled
  const int tid = threadIdx.x;
  const int row0 = blockIdx.x * 64;
#pragma unroll
  for (int i = 0; i < 8; ++i) {
    int c = tid + i * 256;
    int r = c >> 5;
    int c16 = c & 31;
    int grow = row0 + r;
    short8v v = {0, 0, 0, 0, 0, 0, 0, 0};
    if (grow < nrows) {
      const ushort* srcp = (c16 < 16) ? (meanb + (size_t)grow * 128 + c16 * 8)
                                      : (rootb + (size_t)grow * 128 + (c16 - 16) * 8);
      v = *reinterpret_cast<const short8v*>(srcp);
    }
    int dbyte = r * 512 + ((c16 * 16) ^ ((r & 7) << 4));
    *reinterpret_cast<short8v*>(reinterpret_cast<char*>(As) + dbyte) = v;
  }
  __syncthreads();
  const int lane = tid & 63;
  const int rbase = (tid >> 6) * 16;
  const int arow = rbase + (lane & 15);
  const int axor = (arow & 7) << 4;
  const short8v* Wp8 = reinterpret_cast<const short8v*>(Wp);
  float4v acc[8];
#pragma unroll
  for (int f = 0; f < 8; ++f) acc[f] = {0.f, 0.f, 0.f, 0.f};
#pragma unroll
  for (int ks = 0; ks < 8; ++ks) {
    int abyte = arow * 512 + ((ks * 64 + (lane >> 4) * 16) ^ axor);
    short8v a = *reinterpret_cast<const short8v*>(reinterpret_cast<const char*>(As) + abyte);
#pragma unroll
    for (int f = 0; f < 8; ++f) {
      short8v bf = Wp8[(ks * 8 + f) * 64 + lane];
      acc[f] = __builtin_amdgcn_mfma_f32_16x16x32_bf16(a, bf, acc[f], 0, 0, 0);
    }
  }
  const int col_lo = lane & 15;
  const int rq = (lane >> 4) * 4;
#pragma unroll
  for (int f = 0; f < 8; ++f) {
    int col = f * 16 + col_lo;
    float bias = b[col];
#pragma unroll
    for (int r = 0; r < 4; ++r) {
      int row = row0 + rbase + rq + r;
      if (row < nrows) {
        float vv = fmaxf(acc[f][r] + bias, 0.f);
        h[(size_t)row * 128 + col] = f2bf(vv);
      }
    }
  }
}

// ---------------- layer2 projection: p = h@Wl2 (row-major [n][64], round-7) ----------
__global__ __launch_bounds__(256) void k_proj2(const ushort* __restrict__ hb,
                                               const ushort* __restrict__ Wp,
                                               ushort* __restrict__ p, int nrows) {
  __shared__ __align__(16) ushort As[64 * 128];  // 16KB
  const int tid = threadIdx.x;
  const int row0 = blockIdx.x * 64;
#pragma unroll
  for (int i = 0; i < 4; ++i) {
    int c = tid + i * 256;
    int r = c >> 4;
    int c16 = c & 15;
    int grow = row0 + r;
    short8v v = {0, 0, 0, 0, 0, 0, 0, 0};
    if (grow < nrows) v = *reinterpret_cast<const short8v*>(hb + (size_t)grow * 128 + c16 * 8);
    int dbyte = r * 256 + ((c16 * 16) ^ ((r & 7) << 4));
    *reinterpret_cast<short8v*>(reinterpret_cast<char*>(As) + dbyte) = v;
  }
  __syncthreads();
  const int lane = tid & 63;
  const int rbase = (tid >> 6) * 16;
  const int arow = rbase + (lane & 15);
  const int axor = (arow & 7) << 4;
  const short8v* Wp8 = reinterpret_cast<const short8v*>(Wp);
  float4v acc[3];
#pragma unroll
  for (int f = 0; f < 3; ++f) acc[f] = {0.f, 0.f, 0.f, 0.f};
#pragma unroll
  for (int ks = 0; ks < 4; ++ks) {
    int abyte = arow * 256 + ((ks * 64 + (lane >> 4) * 16) ^ axor);
    short8v a = *reinterpret_cast<const short8v*>(reinterpret_cast<const char*>(As) + abyte);
#pragma unroll
    for (int f = 0; f < 3; ++f) {
      short8v bf = Wp8[(ks * 3 + f) * 64 + lane];
      acc[f] = __builtin_amdgcn_mfma_f32_16x16x32_bf16(a, bf, acc[f], 0, 0, 0);
    }
  }
  const int col_lo = lane & 15;
  const int rq = (lane >> 4) * 4;
#pragma unroll
  for (int f = 0; f < 3; ++f) {
    int col = f * 16 + col_lo;
#pragma unroll
    for (int r = 0; r < 4; ++r) {
      int row = row0 + rbase + rq + r;
      if (row < nrows) p[(size_t)row * 64 + col] = f2bf(acc[f][r]);
    }
  }
  // zero cols 48..63
#pragma unroll
  for (int r = 0; r < 4; ++r) {
    int row = row0 + rbase + rq + r;
    if (row < nrows) p[(size_t)row * 64 + 48 + col_lo] = 0;
  }
}

// ---------------- layer2 root: out = h@Wr2 + m + b2 (fp32 out, 40 cols; round-7) -----
__global__ __launch_bounds__(256) void k_root2(const ushort* __restrict__ hb,
                                               const ushort* __restrict__ Wp,
                                               const float* __restrict__ b,
                                               const float* __restrict__ m,
                                               float* __restrict__ out, int nrows) {
  __shared__ __align__(16) ushort As[64 * 128];
  const int tid = threadIdx.x;
  const int row0 = blockIdx.x * 64;
#pragma unroll
  for (int i = 0; i < 4; ++i) {
    int c = tid + i * 256;
    int r = c >> 4;
    int c16 = c & 15;
    int grow = row0 + r;
    short8v v = {0, 0, 0, 0, 0, 0, 0, 0};
    if (grow < nrows) v = *reinterpret_cast<const short8v*>(hb + (size_t)grow * 128 + c16 * 8);
    int dbyte = r * 256 + ((c16 * 16) ^ ((r & 7) << 4));
    *reinterpret_cast<short8v*>(reinterpret_cast<char*>(As) + dbyte) = v;
  }
  __syncthreads();
  const int lane = tid & 63;
  const int rbase = (tid >> 6) * 16;
  const int arow = rbase + (lane & 15);
  const int axor = (arow & 7) << 4;
  const short8v* Wp8 = reinterpret_cast<const short8v*>(Wp);
  float4v acc[3];
#pragma unroll
  for (int f = 0; f < 3; ++f) acc[f] = {0.f, 0.f, 0.f, 0.f};
#pragma unroll
  for (int ks = 0; ks < 4; ++ks) {
    int abyte = arow * 256 + ((ks * 64 + (lane >> 4) * 16) ^ axor);
    short8v a = *reinterpret_cast<const short8v*>(reinterpret_cast<const char*>(As) + abyte);
#pragma unroll
    for (int f = 0; f < 3; ++f) {
      short8v bf = Wp8[(ks * 3 + f) * 64 + lane];
      acc[f] = __builtin_amdgcn_mfma_f32_16x16x32_bf16(a, bf, acc[f], 0, 0, 0);
    }
  }
  const int col_lo = lane & 15;
  const int rq = (lane >> 4) * 4;
#pragma unroll
  for (int f = 0; f < 3; ++f) {
    int col = f * 16 + col_lo;
    if (col < CLSN) {
      float bias = b[col];
#pragma unroll
      for (int r = 0; r < 4; ++r) {
        int row = row0 + rbase + rq + r;
        if (row < nrows)
          out[(size_t)row * CLSN + col] = acc[f][r] + bias + m[(size_t)row * 64 + col];
      }
    }
  }
}

extern "C" void kernel_launch(void* const* d_in, const int* in_sizes, int n_in,
                              void* d_out, int out_size, void* d_ws, size_t ws_size,
                              hipStream_t stream) {
  const float* x = (const float*)d_in[0];
  const int* ei = (const int*)d_in[1];
  const float* Wl1 = (const float*)d_in[2];
  const float* Wr1 = (const float*)d_in[3];
  const float* b1 = (const float*)d_in[4];
  const float* Wl2 = (const float*)d_in[5];
  const float* Wr2 = (const float*)d_in[6];
  const float* b2 = (const float*)d_in[7];
  float* out = (float*)d_out;

  const int n = in_sizes[0] / F;
  const int E = in_sizes[1] / 2;
  const int* src = ei;
  const int* dst = ei + E;

  const int nfine = (n + 511) >> 9;  // 196

  size_t off = 0;
  auto alloc = [&](size_t bytes) {
    size_t cur = off;
    off = (off + bytes + 255) & ~(size_t)255;
    return cur;
  };
  char* w = (char*)d_ws;
  int* offsets = (int*)(w + alloc((size_t)(n + 1) * 4));
  int* srcs = (int*)(w + alloc((size_t)E * 4));
  int* fcur = (int*)(w + alloc(NFINE_MAX * 4));
  int* fbase = (int*)(w + alloc((NFINE_MAX + 1) * 4));
  ushort* xb = (ushort*)(w + alloc((size_t)n * F * 2));
  ushort* hb = (ushort*)(w + alloc((size_t)n * F * 2));
  ushort* meanb = (ushort*)(w + alloc((size_t)n * F * 2));
  ushort* Wp1 = (ushort*)(w + alloc(32768 * 2));
  ushort* Wp2l = (ushort*)(w + alloc(6144 * 2));
  ushort* Wp2r = (ushort*)(w + alloc(6144 * 2));
  (void)ws_size;
  // aliases: pairs (CSR build) and p64 (layer2 projection) live in meanb's region
  // (dead at those times); m64 (fp32, N*64) lives in xb's region (dead after mfma1).
  uint* pairs = (uint*)meanb;
  ushort* p64 = meanb;        // N*64 bf16 = half of meanb region
  float* m64 = (float*)xb;    // N*64 f32 = exactly xb region size

  // casts / weight packing
  k_cast<<<(n * 32 + 255) / 256, 256, 0, stream>>>(x, xb, n * 32);
  k_pack_w1<<<16, 256, 0, stream>>>(Wl1, Wr1, Wp1);
  k_pack_w2pair<<<6, 256, 0, stream>>>(Wl2, Wr2, Wp2l, Wp2r);

  // binned CSR build (one-pass tiled radix partition)
  k_init_fcur<<<1, 256, 0, stream>>>(fcur, nfine);
  k_partition<<<(E + TILE - 1) / TILE, 256, 0, stream>>>(src, dst, fcur, pairs, E);
  k_scan_fine<<<1, 256, 0, stream>>>(fcur, fbase, nfine, E);
  k_local_scatter<<<nfine, 256, 0, stream>>>(pairs, fcur, fbase, offsets, srcs, n, E);

  // layer 1: sliced mean(x) -> h = relu([mean|x]@W1 + b1)
  k_agg_x_s<<<((n + 3) / 4) * 8, 256, 0, stream>>>(xb, offsets, srcs, meanb, n);
  k_mfma1<<<(n + 63) / 64, 256, 0, stream>>>(meanb, xb, Wp1, b1, hb, n);

  // layer 2 (projection-first): p = h@Wl2; m = mean(p); out = h@Wr2 + m + b2
  k_proj2<<<(n + 63) / 64, 256, 0, stream>>>(hb, Wp2l, p64, n);
  k_agg_p_s<<<((n + 3) / 4) * 4, 256, 0, stream>>>(p64, offsets, srcs, m64, n);
  k_root2<<<(n + 63) / 64, 256, 0, stream>>>(hb, Wp2r, b2, m64, out, n);
}

// Round 10
// 223.504 us; speedup vs baseline: 2.3662x; 2.3662x over previous
//
#include <hip/hip_runtime.h>

#define F 128
#define CLSN 40
#define NFINE_MAX 256
#define PCAP 10240
#define TILE 4096
#define STAGE_CAP 10240

typedef __attribute__((ext_vector_type(8))) short short8v;
typedef __attribute__((ext_vector_type(4))) float float4v;

static __device__ inline ushort f2bf(float f) {
  uint u = __float_as_uint(f);
  uint r = (u + 0x7FFFu + ((u >> 16) & 1u)) >> 16;
  return (ushort)r;
}
static __device__ inline float bfLo(uint u) { return __uint_as_float(u << 16); }
static __device__ inline float bfHi(uint u) { return __uint_as_float(u & 0xFFFF0000u); }

// ---------------- casts / packing ----------------
__global__ __launch_bounds__(256) void k_cast(const float* __restrict__ in,
                                              ushort* __restrict__ outb, int nelem4) {
  int i = blockIdx.x * 256 + threadIdx.x;
  if (i < nelem4) {
    float4 v = reinterpret_cast<const float4*>(in)[i];
    ushort4 o;
    o.x = f2bf(v.x); o.y = f2bf(v.y); o.z = f2bf(v.z); o.w = f2bf(v.w);
    reinterpret_cast<ushort4*>(outb)[i] = o;
  }
}

// pack [Wl1;Wr1] (256x128) into MFMA B-frag order: Wp[((ks*8+f)*64+lane)*8+j]
__global__ __launch_bounds__(256) void k_pack_w1(const float* __restrict__ Wl,
                                                 const float* __restrict__ Wr,
                                                 ushort* __restrict__ Wp) {
  int t = blockIdx.x * 256 + threadIdx.x;
  if (t >= 4096) return;
  int lane = t & 63, f = (t >> 6) & 7, ks = t >> 9;
  int col = f * 16 + (lane & 15);
  int k0 = ks * 32 + (lane >> 4) * 8;
#pragma unroll
  for (int j = 0; j < 8; ++j) {
    int k = k0 + j;
    float w = (k < 128) ? Wl[k * 128 + col] : Wr[(k - 128) * 128 + col];
    Wp[t * 8 + j] = f2bf(w);
  }
}

// pack Wl2 and Wr2 (each 128x40, pad cols to 48) as K=128 frags: 4ks x 3f
__global__ __launch_bounds__(256) void k_pack_w2pair(const float* __restrict__ Wl,
                                                     const float* __restrict__ Wr,
                                                     ushort* __restrict__ Wpl,
                                                     ushort* __restrict__ Wpr) {
  int t = blockIdx.x * 256 + threadIdx.x;
  if (t >= 1536) return;
  const float* W = (t < 768) ? Wl : Wr;
  ushort* Wp = (t < 768) ? Wpl : Wpr;
  int tt = (t < 768) ? t : t - 768;
  int lane = tt & 63, rem = tt >> 6;
  int f = rem % 3, ks = rem / 3;
  int col = f * 16 + (lane & 15);
  int k0 = ks * 32 + (lane >> 4) * 8;
#pragma unroll
  for (int j = 0; j < 8; ++j) {
    int k = k0 + j;
    float w = (col < CLSN) ? W[k * CLSN + col] : 0.f;
    Wp[tt * 8 + j] = f2bf(w);
  }
}

// ---------------- one-pass tiled radix partition into fine buckets ----------------
__global__ void k_init_fcur(int* __restrict__ fcur, int nfine) {
  int i = blockIdx.x * 256 + threadIdx.x;
  if (i < nfine) fcur[i] = i * PCAP;
}

__global__ __launch_bounds__(256) void k_partition(const int* __restrict__ src,
                                                   const int* __restrict__ dst,
                                                   int* __restrict__ fcur,
                                                   uint* __restrict__ pairs, int E) {
  __shared__ int hh[NFINE_MAX];
  __shared__ int bb[NFINE_MAX];
  __shared__ unsigned char ebkt[TILE];
  __shared__ ushort dlow[TILE];
  const int tid = threadIdx.x;
  const int tile0 = blockIdx.x * TILE;
  const int lim = min(TILE, E - tile0);
  for (int i = tid; i < NFINE_MAX; i += 256) hh[i] = 0;
  __syncthreads();
  for (int i = tid; i < lim; i += 256) {
    int d = dst[tile0 + i];
    int b = d >> 9;
    ebkt[i] = (unsigned char)b;
    dlow[i] = (ushort)(d & 511);
    atomicAdd(&hh[b], 1);
  }
  __syncthreads();
  for (int i = tid; i < NFINE_MAX; i += 256) {
    int c = hh[i];
    bb[i] = c ? atomicAdd(&fcur[i], c) : 0;
    hh[i] = 0;  // reuse as local cursor
  }
  __syncthreads();
  for (int i = tid; i < lim; i += 256) {
    int b = ebkt[i];
    int r = atomicAdd(&hh[b], 1);
    uint p = (uint)src[tile0 + i] | ((uint)dlow[i] << 17);
    pairs[bb[b] + r] = p;
  }
}

__global__ __launch_bounds__(256) void k_scan_fine(const int* __restrict__ fcur,
                                                   int* __restrict__ fbase,
                                                   int nfine, int E) {
  __shared__ int s[256];
  int tid = threadIdx.x;
  int v = (tid < nfine) ? (fcur[tid] - tid * PCAP) : 0;
  s[tid] = v;
  __syncthreads();
  for (int d = 1; d < 256; d <<= 1) {
    int u = (tid >= d) ? s[tid - d] : 0;
    __syncthreads();
    s[tid] += u;
    __syncthreads();
  }
  if (tid < nfine) fbase[tid] = s[tid] - v;
  if (tid == 0) fbase[nfine] = E;
}

__global__ __launch_bounds__(256) void k_local_scatter(const uint* __restrict__ pairs,
                                                       const int* __restrict__ fcur,
                                                       const int* __restrict__ fbase,
                                                       int* __restrict__ offsets,
                                                       int* __restrict__ srcs,
                                                       int n, int E) {
  __shared__ int s_cnt[512];
  __shared__ int s_scan[512];
  __shared__ int s_stage[STAGE_CAP];
  const int b = blockIdx.x, tid = threadIdx.x;
  const int node0 = b << 9;
  const int pbase = b * PCAP;
  const int ebase = fbase[b];
  const int ecnt = fcur[b] - pbase;
  s_cnt[tid] = 0;
  s_cnt[tid + 256] = 0;
  __syncthreads();
  for (int i = tid; i < ecnt; i += 256) atomicAdd(&s_cnt[pairs[pbase + i] >> 17], 1);
  __syncthreads();
  s_scan[tid] = s_cnt[tid];
  s_scan[tid + 256] = s_cnt[tid + 256];
  __syncthreads();
  for (int d = 1; d < 512; d <<= 1) {
    int v0 = (tid >= d) ? s_scan[tid - d] : 0;
    int v1 = (tid + 256 >= d) ? s_scan[tid + 256 - d] : 0;
    __syncthreads();
    s_scan[tid] += v0;
    s_scan[tid + 256] += v1;
    __syncthreads();
  }
  int e0 = s_scan[tid] - s_cnt[tid];
  int e1 = s_scan[tid + 256] - s_cnt[tid + 256];
  if (node0 + tid < n) offsets[node0 + tid] = ebase + e0;
  if (node0 + tid + 256 < n) offsets[node0 + tid + 256] = ebase + e1;
  if (b == gridDim.x - 1 && tid == 0) offsets[n] = E;
  __syncthreads();
  s_cnt[tid] = e0;
  s_cnt[tid + 256] = e1;
  __syncthreads();
  for (int i = tid; i < ecnt; i += 256) {
    uint p = pairs[pbase + i];
    int v = (int)(p >> 17);
    int s = (int)(p & 0x1FFFFu);
    int pos = atomicAdd(&s_cnt[v], 1);
    if (pos < STAGE_CAP) s_stage[pos] = s;
    else srcs[ebase + pos] = s;
  }
  __syncthreads();
  int lim = min(ecnt, STAGE_CAP);
  for (int i = tid; i < lim; i += 256) srcs[ebase + i] = s_stage[i];
}

// ---------------- mean aggregation: 16-lane group per node, uint4 per lane ----------
// x rows: 256B = 16 lanes x 16B, one full row per group per load instruction.
// 4 nodes/wave, 8-deep unroll -> 32 row-loads in flight per wave.
// Row-major in/out (round-7 layouts).
__global__ __launch_bounds__(256) void k_agg_x(const ushort* __restrict__ feat,
                                               const int* __restrict__ offsets,
                                               const int* __restrict__ srcs,
                                               ushort* __restrict__ mean, int n) {
  const int wid = (blockIdx.x * 256 + threadIdx.x) >> 6;
  const int lane = threadIdx.x & 63;
  const int g = lane >> 4, cl = lane & 15;
  const int node = wid * 4 + g;
  if (node >= n) return;
  const uint4* fp = reinterpret_cast<const uint4*>(feat);
  const int beg = offsets[node];
  const int deg = offsets[node + 1] - beg;
  float a0 = 0.f, a1 = 0.f, a2 = 0.f, a3 = 0.f;
  float a4 = 0.f, a5 = 0.f, a6 = 0.f, a7 = 0.f;
  for (int chunk = 0; chunk < deg; chunk += 16) {
    int cnt = min(16, deg - chunk);
    int s = (cl < cnt) ? srcs[beg + chunk + cl] : 0;
    int k = 0;
    for (; k + 7 < cnt; k += 8) {
      int r0 = __shfl(s, g * 16 + k);
      int r1 = __shfl(s, g * 16 + k + 1);
      int r2 = __shfl(s, g * 16 + k + 2);
      int r3 = __shfl(s, g * 16 + k + 3);
      int r4 = __shfl(s, g * 16 + k + 4);
      int r5 = __shfl(s, g * 16 + k + 5);
      int r6 = __shfl(s, g * 16 + k + 6);
      int r7 = __shfl(s, g * 16 + k + 7);
      uint4 v0 = fp[(size_t)r0 * 16 + cl];
      uint4 v1 = fp[(size_t)r1 * 16 + cl];
      uint4 v2 = fp[(size_t)r2 * 16 + cl];
      uint4 v3 = fp[(size_t)r3 * 16 + cl];
      uint4 v4 = fp[(size_t)r4 * 16 + cl];
      uint4 v5 = fp[(size_t)r5 * 16 + cl];
      uint4 v6 = fp[(size_t)r6 * 16 + cl];
      uint4 v7 = fp[(size_t)r7 * 16 + cl];
      a0 += bfLo(v0.x) + bfLo(v1.x) + bfLo(v2.x) + bfLo(v3.x) +
            bfLo(v4.x) + bfLo(v5.x) + bfLo(v6.x) + bfLo(v7.x);
      a1 += bfHi(v0.x) + bfHi(v1.x) + bfHi(v2.x) + bfHi(v3.x) +
            bfHi(v4.x) + bfHi(v5.x) + bfHi(v6.x) + bfHi(v7.x);
      a2 += bfLo(v0.y) + bfLo(v1.y) + bfLo(v2.y) + bfLo(v3.y) +
            bfLo(v4.y) + bfLo(v5.y) + bfLo(v6.y) + bfLo(v7.y);
      a3 += bfHi(v0.y) + bfHi(v1.y) + bfHi(v2.y) + bfHi(v3.y) +
            bfHi(v4.y) + bfHi(v5.y) + bfHi(v6.y) + bfHi(v7.y);
      a4 += bfLo(v0.z) + bfLo(v1.z) + bfLo(v2.z) + bfLo(v3.z) +
            bfLo(v4.z) + bfLo(v5.z) + bfLo(v6.z) + bfLo(v7.z);
      a5 += bfHi(v0.z) + bfHi(v1.z) + bfHi(v2.z) + bfHi(v3.z) +
            bfHi(v4.z) + bfHi(v5.z) + bfHi(v6.z) + bfHi(v7.z);
      a6 += bfLo(v0.w) + bfLo(v1.w) + bfLo(v2.w) + bfLo(v3.w) +
            bfLo(v4.w) + bfLo(v5.w) + bfLo(v6.w) + bfLo(v7.w);
      a7 += bfHi(v0.w) + bfHi(v1.w) + bfHi(v2.w) + bfHi(v3.w) +
            bfHi(v4.w) + bfHi(v5.w) + bfHi(v6.w) + bfHi(v7.w);
    }
    for (; k < cnt; ++k) {
      int r0 = __shfl(s, g * 16 + k);
      uint4 v0 = fp[(size_t)r0 * 16 + cl];
      a0 += bfLo(v0.x); a1 += bfHi(v0.x);
      a2 += bfLo(v0.y); a3 += bfHi(v0.y);
      a4 += bfLo(v0.z); a5 += bfHi(v0.z);
      a6 += bfLo(v0.w); a7 += bfHi(v0.w);
    }
  }
  float inv = deg > 0 ? 1.f / (float)deg : 0.f;
  uint4 o;
  o.x = (uint)f2bf(a0 * inv) | ((uint)f2bf(a1 * inv) << 16);
  o.y = (uint)f2bf(a2 * inv) | ((uint)f2bf(a3 * inv) << 16);
  o.z = (uint)f2bf(a4 * inv) | ((uint)f2bf(a5 * inv) << 16);
  o.w = (uint)f2bf(a6 * inv) | ((uint)f2bf(a7 * inv) << 16);
  reinterpret_cast<uint4*>(mean)[(size_t)node * 16 + cl] = o;
}

// p rows: 128B = 8 lanes x 16B. 8 nodes/wave, 8-deep unroll. m row-major [n][64] fp32.
__global__ __launch_bounds__(256) void k_agg_p(const ushort* __restrict__ p,
                                               const int* __restrict__ offsets,
                                               const int* __restrict__ srcs,
                                               float* __restrict__ m, int n) {
  const int wid = (blockIdx.x * 256 + threadIdx.x) >> 6;
  const int lane = threadIdx.x & 63;
  const int g = lane >> 3, cl = lane & 7;
  const int node = wid * 8 + g;
  if (node >= n) return;
  const uint4* pp = reinterpret_cast<const uint4*>(p);
  const int beg = offsets[node];
  const int deg = offsets[node + 1] - beg;
  float a0 = 0.f, a1 = 0.f, a2 = 0.f, a3 = 0.f;
  float a4 = 0.f, a5 = 0.f, a6 = 0.f, a7 = 0.f;
  for (int chunk = 0; chunk < deg; chunk += 8) {
    int cnt = min(8, deg - chunk);
    int s = (cl < cnt) ? srcs[beg + chunk + cl] : 0;
    int k = 0;
    for (; k + 7 < cnt; k += 8) {
      int r0 = __shfl(s, g * 8 + k);
      int r1 = __shfl(s, g * 8 + k + 1);
      int r2 = __shfl(s, g * 8 + k + 2);
      int r3 = __shfl(s, g * 8 + k + 3);
      int r4 = __shfl(s, g * 8 + k + 4);
      int r5 = __shfl(s, g * 8 + k + 5);
      int r6 = __shfl(s, g * 8 + k + 6);
      int r7 = __shfl(s, g * 8 + k + 7);
      uint4 v0 = pp[(size_t)r0 * 8 + cl];
      uint4 v1 = pp[(size_t)r1 * 8 + cl];
      uint4 v2 = pp[(size_t)r2 * 8 + cl];
      uint4 v3 = pp[(size_t)r3 * 8 + cl];
      uint4 v4 = pp[(size_t)r4 * 8 + cl];
      uint4 v5 = pp[(size_t)r5 * 8 + cl];
      uint4 v6 = pp[(size_t)r6 * 8 + cl];
      uint4 v7 = pp[(size_t)r7 * 8 + cl];
      a0 += bfLo(v0.x) + bfLo(v1.x) + bfLo(v2.x) + bfLo(v3.x) +
            bfLo(v4.x) + bfLo(v5.x) + bfLo(v6.x) + bfLo(v7.x);
      a1 += bfHi(v0.x) + bfHi(v1.x) + bfHi(v2.x) + bfHi(v3.x) +
            bfHi(v4.x) + bfHi(v5.x) + bfHi(v6.x) + bfHi(v7.x);
      a2 += bfLo(v0.y) + bfLo(v1.y) + bfLo(v2.y) + bfLo(v3.y) +
            bfLo(v4.y) + bfLo(v5.y) + bfLo(v6.y) + bfLo(v7.y);
      a3 += bfHi(v0.y) + bfHi(v1.y) + bfHi(v2.y) + bfHi(v3.y) +
            bfHi(v4.y) + bfHi(v5.y) + bfHi(v6.y) + bfHi(v7.y);
      a4 += bfLo(v0.z) + bfLo(v1.z) + bfLo(v2.z) + bfLo(v3.z) +
            bfLo(v4.z) + bfLo(v5.z) + bfLo(v6.z) + bfLo(v7.z);
      a5 += bfHi(v0.z) + bfHi(v1.z) + bfHi(v2.z) + bfHi(v3.z) +
            bfHi(v4.z) + bfHi(v5.z) + bfHi(v6.z) + bfHi(v7.z);
      a6 += bfLo(v0.w) + bfLo(v1.w) + bfLo(v2.w) + bfLo(v3.w) +
            bfLo(v4.w) + bfLo(v5.w) + bfLo(v6.w) + bfLo(v7.w);
      a7 += bfHi(v0.w) + bfHi(v1.w) + bfHi(v2.w) + bfHi(v3.w) +
            bfHi(v4.w) + bfHi(v5.w) + bfHi(v6.w) + bfHi(v7.w);
    }
    for (; k < cnt; ++k) {
      int r0 = __shfl(s, g * 8 + k);
      uint4 v0 = pp[(size_t)r0 * 8 + cl];
      a0 += bfLo(v0.x); a1 += bfHi(v0.x);
      a2 += bfLo(v0.y); a3 += bfHi(v0.y);
      a4 += bfLo(v0.z); a5 += bfHi(v0.z);
      a6 += bfLo(v0.w); a7 += bfHi(v0.w);
    }
  }
  float inv = deg > 0 ? 1.f / (float)deg : 0.f;
  float4* mp = reinterpret_cast<float4*>(m);
  mp[(size_t)node * 16 + cl * 2] = make_float4(a0 * inv, a1 * inv, a2 * inv, a3 * inv);
  mp[(size_t)node * 16 + cl * 2 + 1] = make_float4(a4 * inv, a5 * inv, a6 * inv, a7 * inv);
}

// ---------------- layer1 MFMA GEMM: h = relu([mean|x]@Wp1 + b1), bf16 out ------------
__global__ __launch_bounds__(256) void k_mfma1(const ushort* __restrict__ meanb,
                                               const ushort* __restrict__ rootb,
                                               const ushort* __restrict__ Wp,
                                               const float* __restrict__ b,
                                               ushort* __restrict__ h, int nrows) {
  __shared__ __align__(16) ushort As[64 * 256];  // 32KB, XOR-swizzled
  const int tid = threadIdx.x;
  const int row0 = blockIdx.x * 64;
#pragma unroll
  for (int i = 0; i < 8; ++i) {
    int c = tid + i * 256;
    int r = c >> 5;
    int c16 = c & 31;
    int grow = row0 + r;
    short8v v = {0, 0, 0, 0, 0, 0, 0, 0};
    if (grow < nrows) {
      const ushort* srcp = (c16 < 16) ? (meanb + (size_t)grow * 128 + c16 * 8)
                                      : (rootb + (size_t)grow * 128 + (c16 - 16) * 8);
      v = *reinterpret_cast<const short8v*>(srcp);
    }
    int dbyte = r * 512 + ((c16 * 16) ^ ((r & 7) << 4));
    *reinterpret_cast<short8v*>(reinterpret_cast<char*>(As) + dbyte) = v;
  }
  __syncthreads();
  const int lane = tid & 63;
  const int rbase = (tid >> 6) * 16;
  const int arow = rbase + (lane & 15);
  const int axor = (arow & 7) << 4;
  const short8v* Wp8 = reinterpret_cast<const short8v*>(Wp);
  float4v acc[8];
#pragma unroll
  for (int f = 0; f < 8; ++f) acc[f] = {0.f, 0.f, 0.f, 0.f};
#pragma unroll
  for (int ks = 0; ks < 8; ++ks) {
    int abyte = arow * 512 + ((ks * 64 + (lane >> 4) * 16) ^ axor);
    short8v a = *reinterpret_cast<const short8v*>(reinterpret_cast<const char*>(As) + abyte);
#pragma unroll
    for (int f = 0; f < 8; ++f) {
      short8v bf = Wp8[(ks * 8 + f) * 64 + lane];
      acc[f] = __builtin_amdgcn_mfma_f32_16x16x32_bf16(a, bf, acc[f], 0, 0, 0);
    }
  }
  const int col_lo = lane & 15;
  const int rq = (lane >> 4) * 4;
#pragma unroll
  for (int f = 0; f < 8; ++f) {
    int col = f * 16 + col_lo;
    float bias = b[col];
#pragma unroll
    for (int r = 0; r < 4; ++r) {
      int row = row0 + rbase + rq + r;
      if (row < nrows) {
        float vv = fmaxf(acc[f][r] + bias, 0.f);
        h[(size_t)row * 128 + col] = f2bf(vv);
      }
    }
  }
}

// ---------------- layer2 projection: p = h@Wl2 (row-major [n][64]) ------------------
__global__ __launch_bounds__(256) void k_proj2(const ushort* __restrict__ hb,
                                               const ushort* __restrict__ Wp,
                                               ushort* __restrict__ p, int nrows) {
  __shared__ __align__(16) ushort As[64 * 128];  // 16KB
  const int tid = threadIdx.x;
  const int row0 = blockIdx.x * 64;
#pragma unroll
  for (int i = 0; i < 4; ++i) {
    int c = tid + i * 256;
    int r = c >> 4;
    int c16 = c & 15;
    int grow = row0 + r;
    short8v v = {0, 0, 0, 0, 0, 0, 0, 0};
    if (grow < nrows) v = *reinterpret_cast<const short8v*>(hb + (size_t)grow * 128 + c16 * 8);
    int dbyte = r * 256 + ((c16 * 16) ^ ((r & 7) << 4));
    *reinterpret_cast<short8v*>(reinterpret_cast<char*>(As) + dbyte) = v;
  }
  __syncthreads();
  const int lane = tid & 63;
  const int rbase = (tid >> 6) * 16;
  const int arow = rbase + (lane & 15);
  const int axor = (arow & 7) << 4;
  const short8v* Wp8 = reinterpret_cast<const short8v*>(Wp);
  float4v acc[3];
#pragma unroll
  for (int f = 0; f < 3; ++f) acc[f] = {0.f, 0.f, 0.f, 0.f};
#pragma unroll
  for (int ks = 0; ks < 4; ++ks) {
    int abyte = arow * 256 + ((ks * 64 + (lane >> 4) * 16) ^ axor);
    short8v a = *reinterpret_cast<const short8v*>(reinterpret_cast<const char*>(As) + abyte);
#pragma unroll
    for (int f = 0; f < 3; ++f) {
      short8v bf = Wp8[(ks * 3 + f) * 64 + lane];
      acc[f] = __builtin_amdgcn_mfma_f32_16x16x32_bf16(a, bf, acc[f], 0, 0, 0);
    }
  }
  const int col_lo = lane & 15;
  const int rq = (lane >> 4) * 4;
#pragma unroll
  for (int f = 0; f < 3; ++f) {
    int col = f * 16 + col_lo;
#pragma unroll
    for (int r = 0; r < 4; ++r) {
      int row = row0 + rbase + rq + r;
      if (row < nrows) p[(size_t)row * 64 + col] = f2bf(acc[f][r]);
    }
  }
  // zero cols 48..63
#pragma unroll
  for (int r = 0; r < 4; ++r) {
    int row = row0 + rbase + rq + r;
    if (row < nrows) p[(size_t)row * 64 + 48 + col_lo] = 0;
  }
}

// ---------------- layer2 root: out = h@Wr2 + m + b2 (fp32 out, 40 cols) --------------
__global__ __launch_bounds__(256) void k_root2(const ushort* __restrict__ hb,
                                               const ushort* __restrict__ Wp,
                                               const float* __restrict__ b,
                                               const float* __restrict__ m,
                                               float* __restrict__ out, int nrows) {
  __shared__ __align__(16) ushort As[64 * 128];
  const int tid = threadIdx.x;
  const int row0 = blockIdx.x * 64;
#pragma unroll
  for (int i = 0; i < 4; ++i) {
    int c = tid + i * 256;
    int r = c >> 4;
    int c16 = c & 15;
    int grow = row0 + r;
    short8v v = {0, 0, 0, 0, 0, 0, 0, 0};
    if (grow < nrows) v = *reinterpret_cast<const short8v*>(hb + (size_t)grow * 128 + c16 * 8);
    int dbyte = r * 256 + ((c16 * 16) ^ ((r & 7) << 4));
    *reinterpret_cast<short8v*>(reinterpret_cast<char*>(As) + dbyte) = v;
  }
  __syncthreads();
  const int lane = tid & 63;
  const int rbase = (tid >> 6) * 16;
  const int arow = rbase + (lane & 15);
  const int axor = (arow & 7) << 4;
  const short8v* Wp8 = reinterpret_cast<const short8v*>(Wp);
  float4v acc[3];
#pragma unroll
  for (int f = 0; f < 3; ++f) acc[f] = {0.f, 0.f, 0.f, 0.f};
#pragma unroll
  for (int ks = 0; ks < 4; ++ks) {
    int abyte = arow * 256 + ((ks * 64 + (lane >> 4) * 16) ^ axor);
    short8v a = *reinterpret_cast<const short8v*>(reinterpret_cast<const char*>(As) + abyte);
#pragma unroll
    for (int f = 0; f < 3; ++f) {
      short8v bf = Wp8[(ks * 3 + f) * 64 + lane];
      acc[f] = __builtin_amdgcn_mfma_f32_16x16x32_bf16(a, bf, acc[f], 0, 0, 0);
    }
  }
  const int col_lo = lane & 15;
  const int rq = (lane >> 4) * 4;
#pragma unroll
  for (int f = 0; f < 3; ++f) {
    int col = f * 16 + col_lo;
    if (col < CLSN) {
      float bias = b[col];
#pragma unroll
      for (int r = 0; r < 4; ++r) {
        int row = row0 + rbase + rq + r;
        if (row < nrows)
          out[(size_t)row * CLSN + col] = acc[f][r] + bias + m[(size_t)row * 64 + col];
      }
    }
  }
}

extern "C" void kernel_launch(void* const* d_in, const int* in_sizes, int n_in,
                              void* d_out, int out_size, void* d_ws, size_t ws_size,
                              hipStream_t stream) {
  const float* x = (const float*)d_in[0];
  const int* ei = (const int*)d_in[1];
  const float* Wl1 = (const float*)d_in[2];
  const float* Wr1 = (const float*)d_in[3];
  const float* b1 = (const float*)d_in[4];
  const float* Wl2 = (const float*)d_in[5];
  const float* Wr2 = (const float*)d_in[6];
  const float* b2 = (const float*)d_in[7];
  float* out = (float*)d_out;

  const int n = in_sizes[0] / F;
  const int E = in_sizes[1] / 2;
  const int* src = ei;
  const int* dst = ei + E;

  const int nfine = (n + 511) >> 9;  // 196

  size_t off = 0;
  auto alloc = [&](size_t bytes) {
    size_t cur = off;
    off = (off + bytes + 255) & ~(size_t)255;
    return cur;
  };
  char* w = (char*)d_ws;
  int* offsets = (int*)(w + alloc((size_t)(n + 1) * 4));
  int* srcs = (int*)(w + alloc((size_t)E * 4));
  int* fcur = (int*)(w + alloc(NFINE_MAX * 4));
  int* fbase = (int*)(w + alloc((NFINE_MAX + 1) * 4));
  ushort* xb = (ushort*)(w + alloc((size_t)n * F * 2));
  ushort* hb = (ushort*)(w + alloc((size_t)n * F * 2));
  ushort* meanb = (ushort*)(w + alloc((size_t)n * F * 2));
  ushort* Wp1 = (ushort*)(w + alloc(32768 * 2));
  ushort* Wp2l = (ushort*)(w + alloc(6144 * 2));
  ushort* Wp2r = (ushort*)(w + alloc(6144 * 2));
  (void)ws_size;
  // aliases: pairs (CSR build) and p64 (layer2 projection) live in meanb's region
  // (dead at those times); m64 (fp32, N*64) lives in xb's region (dead after mfma1).
  uint* pairs = (uint*)meanb;
  ushort* p64 = meanb;        // N*64 bf16 = half of meanb region
  float* m64 = (float*)xb;    // N*64 f32 = exactly xb region size

  // casts / weight packing
  k_cast<<<(n * 32 + 255) / 256, 256, 0, stream>>>(x, xb, n * 32);
  k_pack_w1<<<16, 256, 0, stream>>>(Wl1, Wr1, Wp1);
  k_pack_w2pair<<<6, 256, 0, stream>>>(Wl2, Wr2, Wp2l, Wp2r);

  // binned CSR build (one-pass tiled radix partition)
  k_init_fcur<<<1, 256, 0, stream>>>(fcur, nfine);
  k_partition<<<(E + TILE - 1) / TILE, 256, 0, stream>>>(src, dst, fcur, pairs, E);
  k_scan_fine<<<1, 256, 0, stream>>>(fcur, fbase, nfine, E);
  k_local_scatter<<<nfine, 256, 0, stream>>>(pairs, fcur, fbase, offsets, srcs, n, E);

  // layer 1: mean(x) -> h = relu([mean|x]@W1 + b1)
  k_agg_x<<<(n + 15) / 16, 256, 0, stream>>>(xb, offsets, srcs, meanb, n);
  k_mfma1<<<(n + 63) / 64, 256, 0, stream>>>(meanb, xb, Wp1, b1, hb, n);

  // layer 2 (projection-first): p = h@Wl2; m = mean(p); out = h@Wr2 + m + b2
  k_proj2<<<(n + 63) / 64, 256, 0, stream>>>(hb, Wp2l, p64, n);
  k_agg_p<<<(n + 31) / 32, 256, 0, stream>>>(p64, offsets, srcs, m64, n);
  k_root2<<<(n + 63) / 64, 256, 0, stream>>>(hb, Wp2r, b2, m64, out, n);
}

// Round 11
// 201.381 us; speedup vs baseline: 2.6262x; 1.1099x over previous
//
#include <hip/hip_runtime.h>

#define F 128
#define CLSN 40
#define NFINE_MAX 256
#define PCAP 10240
#define TILE 4096
#define STAGE_CAP 10240
#define QSCALE 22.0f

typedef __attribute__((ext_vector_type(8))) short short8v;
typedef __attribute__((ext_vector_type(4))) float float4v;

static __device__ inline ushort f2bf(float f) {
  uint u = __float_as_uint(f);
  uint r = (u + 0x7FFFu + ((u >> 16) & 1u)) >> 16;
  return (ushort)r;
}
static __device__ inline float bfLo(uint u) { return __uint_as_float(u << 16); }
static __device__ inline float bfHi(uint u) { return __uint_as_float(u & 0xFFFF0000u); }
static __device__ inline int sb(uint v, int sh) { return (int)(signed char)(v >> sh); }
static __device__ inline unsigned char q8(float f) {
  float t = rintf(f * QSCALE);
  t = fminf(fmaxf(t, -127.f), 127.f);
  return (unsigned char)(signed char)(int)t;
}

// ---------------- casts / packing ----------------
__global__ __launch_bounds__(256) void k_cast(const float* __restrict__ in,
                                              ushort* __restrict__ outb,
                                              unsigned char* __restrict__ outq, int nelem4) {
  int i = blockIdx.x * 256 + threadIdx.x;
  if (i < nelem4) {
    float4 v = reinterpret_cast<const float4*>(in)[i];
    ushort4 o;
    o.x = f2bf(v.x); o.y = f2bf(v.y); o.z = f2bf(v.z); o.w = f2bf(v.w);
    reinterpret_cast<ushort4*>(outb)[i] = o;
    uchar4 q;
    q.x = q8(v.x); q.y = q8(v.y); q.z = q8(v.z); q.w = q8(v.w);
    reinterpret_cast<uchar4*>(outq)[i] = q;
  }
}

// pack [Wl1;Wr1] (256x128) into MFMA B-frag order: Wp[((ks*8+f)*64+lane)*8+j]
__global__ __launch_bounds__(256) void k_pack_w1(const float* __restrict__ Wl,
                                                 const float* __restrict__ Wr,
                                                 ushort* __restrict__ Wp) {
  int t = blockIdx.x * 256 + threadIdx.x;
  if (t >= 4096) return;
  int lane = t & 63, f = (t >> 6) & 7, ks = t >> 9;
  int col = f * 16 + (lane & 15);
  int k0 = ks * 32 + (lane >> 4) * 8;
#pragma unroll
  for (int j = 0; j < 8; ++j) {
    int k = k0 + j;
    float w = (k < 128) ? Wl[k * 128 + col] : Wr[(k - 128) * 128 + col];
    Wp[t * 8 + j] = f2bf(w);
  }
}

// pack Wl2 and Wr2 (each 128x40, pad cols to 48) as K=128 frags: 4ks x 3f
__global__ __launch_bounds__(256) void k_pack_w2pair(const float* __restrict__ Wl,
                                                     const float* __restrict__ Wr,
                                                     ushort* __restrict__ Wpl,
                                                     ushort* __restrict__ Wpr) {
  int t = blockIdx.x * 256 + threadIdx.x;
  if (t >= 1536) return;
  const float* W = (t < 768) ? Wl : Wr;
  ushort* Wp = (t < 768) ? Wpl : Wpr;
  int tt = (t < 768) ? t : t - 768;
  int lane = tt & 63, rem = tt >> 6;
  int f = rem % 3, ks = rem / 3;
  int col = f * 16 + (lane & 15);
  int k0 = ks * 32 + (lane >> 4) * 8;
#pragma unroll
  for (int j = 0; j < 8; ++j) {
    int k = k0 + j;
    float w = (col < CLSN) ? W[k * CLSN + col] : 0.f;
    Wp[tt * 8 + j] = f2bf(w);
  }
}

// ---------------- one-pass tiled radix partition into fine buckets ----------------
__global__ void k_init_fcur(int* __restrict__ fcur, int nfine) {
  int i = blockIdx.x * 256 + threadIdx.x;
  if (i < nfine) fcur[i] = i * PCAP;
}

__global__ __launch_bounds__(256) void k_partition(const int* __restrict__ src,
                                                   const int* __restrict__ dst,
                                                   int* __restrict__ fcur,
                                                   uint* __restrict__ pairs, int E) {
  __shared__ int hh[NFINE_MAX];
  __shared__ int bb[NFINE_MAX];
  __shared__ unsigned char ebkt[TILE];
  __shared__ ushort dlow[TILE];
  const int tid = threadIdx.x;
  const int tile0 = blockIdx.x * TILE;
  const int lim = min(TILE, E - tile0);
  for (int i = tid; i < NFINE_MAX; i += 256) hh[i] = 0;
  __syncthreads();
  for (int i = tid; i < lim; i += 256) {
    int d = dst[tile0 + i];
    int b = d >> 9;
    ebkt[i] = (unsigned char)b;
    dlow[i] = (ushort)(d & 511);
    atomicAdd(&hh[b], 1);
  }
  __syncthreads();
  for (int i = tid; i < NFINE_MAX; i += 256) {
    int c = hh[i];
    bb[i] = c ? atomicAdd(&fcur[i], c) : 0;
    hh[i] = 0;  // reuse as local cursor
  }
  __syncthreads();
  for (int i = tid; i < lim; i += 256) {
    int b = ebkt[i];
    int r = atomicAdd(&hh[b], 1);
    uint p = (uint)src[tile0 + i] | ((uint)dlow[i] << 17);
    pairs[bb[b] + r] = p;
  }
}

__global__ __launch_bounds__(256) void k_scan_fine(const int* __restrict__ fcur,
                                                   int* __restrict__ fbase,
                                                   int nfine, int E) {
  __shared__ int s[256];
  int tid = threadIdx.x;
  int v = (tid < nfine) ? (fcur[tid] - tid * PCAP) : 0;
  s[tid] = v;
  __syncthreads();
  for (int d = 1; d < 256; d <<= 1) {
    int u = (tid >= d) ? s[tid - d] : 0;
    __syncthreads();
    s[tid] += u;
    __syncthreads();
  }
  if (tid < nfine) fbase[tid] = s[tid] - v;
  if (tid == 0) fbase[nfine] = E;
}

__global__ __launch_bounds__(256) void k_local_scatter(const uint* __restrict__ pairs,
                                                       const int* __restrict__ fcur,
                                                       const int* __restrict__ fbase,
                                                       int* __restrict__ offsets,
                                                       int* __restrict__ srcs,
                                                       int n, int E) {
  __shared__ int s_cnt[512];
  __shared__ int s_scan[512];
  __shared__ int s_stage[STAGE_CAP];
  const int b = blockIdx.x, tid = threadIdx.x;
  const int node0 = b << 9;
  const int pbase = b * PCAP;
  const int ebase = fbase[b];
  const int ecnt = fcur[b] - pbase;
  s_cnt[tid] = 0;
  s_cnt[tid + 256] = 0;
  __syncthreads();
  for (int i = tid; i < ecnt; i += 256) atomicAdd(&s_cnt[pairs[pbase + i] >> 17], 1);
  __syncthreads();
  s_scan[tid] = s_cnt[tid];
  s_scan[tid + 256] = s_cnt[tid + 256];
  __syncthreads();
  for (int d = 1; d < 512; d <<= 1) {
    int v0 = (tid >= d) ? s_scan[tid - d] : 0;
    int v1 = (tid + 256 >= d) ? s_scan[tid + 256 - d] : 0;
    __syncthreads();
    s_scan[tid] += v0;
    s_scan[tid + 256] += v1;
    __syncthreads();
  }
  int e0 = s_scan[tid] - s_cnt[tid];
  int e1 = s_scan[tid + 256] - s_cnt[tid + 256];
  if (node0 + tid < n) offsets[node0 + tid] = ebase + e0;
  if (node0 + tid + 256 < n) offsets[node0 + tid + 256] = ebase + e1;
  if (b == gridDim.x - 1 && tid == 0) offsets[n] = E;
  __syncthreads();
  s_cnt[tid] = e0;
  s_cnt[tid + 256] = e1;
  __syncthreads();
  for (int i = tid; i < ecnt; i += 256) {
    uint p = pairs[pbase + i];
    int v = (int)(p >> 17);
    int s = (int)(p & 0x1FFFFu);
    int pos = atomicAdd(&s_cnt[v], 1);
    if (pos < STAGE_CAP) s_stage[pos] = s;
    else srcs[ebase + pos] = s;
  }
  __syncthreads();
  int lim = min(ecnt, STAGE_CAP);
  for (int i = tid; i < lim; i += 256) srcs[ebase + i] = s_stage[i];
}

// ---------------- mean aggregation, layer 1: int8 rows (128B), int accumulate -------
// 16-lane group per node, uint2 (8 int8 feats) per lane; 4 nodes/wave; 8-deep unroll.
// mean out: bf16 row-major [n][128] (round-10 layout).
__global__ __launch_bounds__(256) void k_agg_x(const unsigned char* __restrict__ xq,
                                               const int* __restrict__ offsets,
                                               const int* __restrict__ srcs,
                                               ushort* __restrict__ mean, int n) {
  const int wid = (blockIdx.x * 256 + threadIdx.x) >> 6;
  const int lane = threadIdx.x & 63;
  const int g = lane >> 4, cl = lane & 15;
  const int node = wid * 4 + g;
  if (node >= n) return;
  const uint2* fp = reinterpret_cast<const uint2*>(xq);  // row = 16 uint2
  const int beg = offsets[node];
  const int deg = offsets[node + 1] - beg;
  int s0 = 0, s1 = 0, s2 = 0, s3 = 0, s4 = 0, s5 = 0, s6 = 0, s7 = 0;
  for (int chunk = 0; chunk < deg; chunk += 16) {
    int cnt = min(16, deg - chunk);
    int s = (cl < cnt) ? srcs[beg + chunk + cl] : 0;
    int k = 0;
    for (; k + 7 < cnt; k += 8) {
      int r0 = __shfl(s, g * 16 + k);
      int r1 = __shfl(s, g * 16 + k + 1);
      int r2 = __shfl(s, g * 16 + k + 2);
      int r3 = __shfl(s, g * 16 + k + 3);
      int r4 = __shfl(s, g * 16 + k + 4);
      int r5 = __shfl(s, g * 16 + k + 5);
      int r6 = __shfl(s, g * 16 + k + 6);
      int r7 = __shfl(s, g * 16 + k + 7);
      uint2 v0 = fp[(size_t)r0 * 16 + cl];
      uint2 v1 = fp[(size_t)r1 * 16 + cl];
      uint2 v2 = fp[(size_t)r2 * 16 + cl];
      uint2 v3 = fp[(size_t)r3 * 16 + cl];
      uint2 v4 = fp[(size_t)r4 * 16 + cl];
      uint2 v5 = fp[(size_t)r5 * 16 + cl];
      uint2 v6 = fp[(size_t)r6 * 16 + cl];
      uint2 v7 = fp[(size_t)r7 * 16 + cl];
      s0 += sb(v0.x, 0) + sb(v1.x, 0) + sb(v2.x, 0) + sb(v3.x, 0) +
            sb(v4.x, 0) + sb(v5.x, 0) + sb(v6.x, 0) + sb(v7.x, 0);
      s1 += sb(v0.x, 8) + sb(v1.x, 8) + sb(v2.x, 8) + sb(v3.x, 8) +
            sb(v4.x, 8) + sb(v5.x, 8) + sb(v6.x, 8) + sb(v7.x, 8);
      s2 += sb(v0.x, 16) + sb(v1.x, 16) + sb(v2.x, 16) + sb(v3.x, 16) +
            sb(v4.x, 16) + sb(v5.x, 16) + sb(v6.x, 16) + sb(v7.x, 16);
      s3 += sb(v0.x, 24) + sb(v1.x, 24) + sb(v2.x, 24) + sb(v3.x, 24) +
            sb(v4.x, 24) + sb(v5.x, 24) + sb(v6.x, 24) + sb(v7.x, 24);
      s4 += sb(v0.y, 0) + sb(v1.y, 0) + sb(v2.y, 0) + sb(v3.y, 0) +
            sb(v4.y, 0) + sb(v5.y, 0) + sb(v6.y, 0) + sb(v7.y, 0);
      s5 += sb(v0.y, 8) + sb(v1.y, 8) + sb(v2.y, 8) + sb(v3.y, 8) +
            sb(v4.y, 8) + sb(v5.y, 8) + sb(v6.y, 8) + sb(v7.y, 8);
      s6 += sb(v0.y, 16) + sb(v1.y, 16) + sb(v2.y, 16) + sb(v3.y, 16) +
            sb(v4.y, 16) + sb(v5.y, 16) + sb(v6.y, 16) + sb(v7.y, 16);
      s7 += sb(v0.y, 24) + sb(v1.y, 24) + sb(v2.y, 24) + sb(v3.y, 24) +
            sb(v4.y, 24) + sb(v5.y, 24) + sb(v6.y, 24) + sb(v7.y, 24);
    }
    for (; k < cnt; ++k) {
      int r0 = __shfl(s, g * 16 + k);
      uint2 v0 = fp[(size_t)r0 * 16 + cl];
      s0 += sb(v0.x, 0); s1 += sb(v0.x, 8);
      s2 += sb(v0.x, 16); s3 += sb(v0.x, 24);
      s4 += sb(v0.y, 0); s5 += sb(v0.y, 8);
      s6 += sb(v0.y, 16); s7 += sb(v0.y, 24);
    }
  }
  float inv = deg > 0 ? 1.f / (QSCALE * (float)deg) : 0.f;
  uint4 o;
  o.x = (uint)f2bf((float)s0 * inv) | ((uint)f2bf((float)s1 * inv) << 16);
  o.y = (uint)f2bf((float)s2 * inv) | ((uint)f2bf((float)s3 * inv) << 16);
  o.z = (uint)f2bf((float)s4 * inv) | ((uint)f2bf((float)s5 * inv) << 16);
  o.w = (uint)f2bf((float)s6 * inv) | ((uint)f2bf((float)s7 * inv) << 16);
  reinterpret_cast<uint4*>(mean)[(size_t)node * 16 + cl] = o;
}

// p rows: 128B bf16 = 8 lanes x 16B. 8 nodes/wave. m row-major [n][64] fp32.
__global__ __launch_bounds__(256) void k_agg_p(const ushort* __restrict__ p,
                                               const int* __restrict__ offsets,
                                               const int* __restrict__ srcs,
                                               float* __restrict__ m, int n) {
  const int wid = (blockIdx.x * 256 + threadIdx.x) >> 6;
  const int lane = threadIdx.x & 63;
  const int g = lane >> 3, cl = lane & 7;
  const int node = wid * 8 + g;
  if (node >= n) return;
  const uint4* pp = reinterpret_cast<const uint4*>(p);
  const int beg = offsets[node];
  const int deg = offsets[node + 1] - beg;
  float a0 = 0.f, a1 = 0.f, a2 = 0.f, a3 = 0.f;
  float a4 = 0.f, a5 = 0.f, a6 = 0.f, a7 = 0.f;
  for (int chunk = 0; chunk < deg; chunk += 8) {
    int cnt = min(8, deg - chunk);
    int s = (cl < cnt) ? srcs[beg + chunk + cl] : 0;
    int k = 0;
    for (; k + 7 < cnt; k += 8) {
      int r0 = __shfl(s, g * 8 + k);
      int r1 = __shfl(s, g * 8 + k + 1);
      int r2 = __shfl(s, g * 8 + k + 2);
      int r3 = __shfl(s, g * 8 + k + 3);
      int r4 = __shfl(s, g * 8 + k + 4);
      int r5 = __shfl(s, g * 8 + k + 5);
      int r6 = __shfl(s, g * 8 + k + 6);
      int r7 = __shfl(s, g * 8 + k + 7);
      uint4 v0 = pp[(size_t)r0 * 8 + cl];
      uint4 v1 = pp[(size_t)r1 * 8 + cl];
      uint4 v2 = pp[(size_t)r2 * 8 + cl];
      uint4 v3 = pp[(size_t)r3 * 8 + cl];
      uint4 v4 = pp[(size_t)r4 * 8 + cl];
      uint4 v5 = pp[(size_t)r5 * 8 + cl];
      uint4 v6 = pp[(size_t)r6 * 8 + cl];
      uint4 v7 = pp[(size_t)r7 * 8 + cl];
      a0 += bfLo(v0.x) + bfLo(v1.x) + bfLo(v2.x) + bfLo(v3.x) +
            bfLo(v4.x) + bfLo(v5.x) + bfLo(v6.x) + bfLo(v7.x);
      a1 += bfHi(v0.x) + bfHi(v1.x) + bfHi(v2.x) + bfHi(v3.x) +
            bfHi(v4.x) + bfHi(v5.x) + bfHi(v6.x) + bfHi(v7.x);
      a2 += bfLo(v0.y) + bfLo(v1.y) + bfLo(v2.y) + bfLo(v3.y) +
            bfLo(v4.y) + bfLo(v5.y) + bfLo(v6.y) + bfLo(v7.y);
      a3 += bfHi(v0.y) + bfHi(v1.y) + bfHi(v2.y) + bfHi(v3.y) +
            bfHi(v4.y) + bfHi(v5.y) + bfHi(v6.y) + bfHi(v7.y);
      a4 += bfLo(v0.z) + bfLo(v1.z) + bfLo(v2.z) + bfLo(v3.z) +
            bfLo(v4.z) + bfLo(v5.z) + bfLo(v6.z) + bfLo(v7.z);
      a5 += bfHi(v0.z) + bfHi(v1.z) + bfHi(v2.z) + bfHi(v3.z) +
            bfHi(v4.z) + bfHi(v5.z) + bfHi(v6.z) + bfHi(v7.z);
      a6 += bfLo(v0.w) + bfLo(v1.w) + bfLo(v2.w) + bfLo(v3.w) +
            bfLo(v4.w) + bfLo(v5.w) + bfLo(v6.w) + bfLo(v7.w);
      a7 += bfHi(v0.w) + bfHi(v1.w) + bfHi(v2.w) + bfHi(v3.w) +
            bfHi(v4.w) + bfHi(v5.w) + bfHi(v6.w) + bfHi(v7.w);
    }
    for (; k < cnt; ++k) {
      int r0 = __shfl(s, g * 8 + k);
      uint4 v0 = pp[(size_t)r0 * 8 + cl];
      a0 += bfLo(v0.x); a1 += bfHi(v0.x);
      a2 += bfLo(v0.y); a3 += bfHi(v0.y);
      a4 += bfLo(v0.z); a5 += bfHi(v0.z);
      a6 += bfLo(v0.w); a7 += bfHi(v0.w);
    }
  }
  float inv = deg > 0 ? 1.f / (float)deg : 0.f;
  float4* mp = reinterpret_cast<float4*>(m);
  mp[(size_t)node * 16 + cl * 2] = make_float4(a0 * inv, a1 * inv, a2 * inv, a3 * inv);
  mp[(size_t)node * 16 + cl * 2 + 1] = make_float4(a4 * inv, a5 * inv, a6 * inv, a7 * inv);
}

// ---------------- layer1 MFMA GEMM: h = relu([mean|x]@Wp1 + b1), bf16 out ------------
__global__ __launch_bounds__(256) void k_mfma1(const ushort* __restrict__ meanb,
                                               const ushort* __restrict__ rootb,
                                               const ushort* __restrict__ Wp,
                                               const float* __restrict__ b,
                                               ushort* __restrict__ h, int nrows) {
  __shared__ __align__(16) ushort As[64 * 256];  // 32KB, XOR-swizzled
  const int tid = threadIdx.x;
  const int row0 = blockIdx.x * 64;
#pragma unroll
  for (int i = 0; i < 8; ++i) {
    int c = tid + i * 256;
    int r = c >> 5;
    int c16 = c & 31;
    int grow = row0 + r;
    short8v v = {0, 0, 0, 0, 0, 0, 0, 0};
    if (grow < nrows) {
      const ushort* srcp = (c16 < 16) ? (meanb + (size_t)grow * 128 + c16 * 8)
                                      : (rootb + (size_t)grow * 128 + (c16 - 16) * 8);
      v = *reinterpret_cast<const short8v*>(srcp);
    }
    int dbyte = r * 512 + ((c16 * 16) ^ ((r & 7) << 4));
    *reinterpret_cast<short8v*>(reinterpret_cast<char*>(As) + dbyte) = v;
  }
  __syncthreads();
  const int lane = tid & 63;
  const int rbase = (tid >> 6) * 16;
  const int arow = rbase + (lane & 15);
  const int axor = (arow & 7) << 4;
  const short8v* Wp8 = reinterpret_cast<const short8v*>(Wp);
  float4v acc[8];
#pragma unroll
  for (int f = 0; f < 8; ++f) acc[f] = {0.f, 0.f, 0.f, 0.f};
#pragma unroll
  for (int ks = 0; ks < 8; ++ks) {
    int abyte = arow * 512 + ((ks * 64 + (lane >> 4) * 16) ^ axor);
    short8v a = *reinterpret_cast<const short8v*>(reinterpret_cast<const char*>(As) + abyte);
#pragma unroll
    for (int f = 0; f < 8; ++f) {
      short8v bf = Wp8[(ks * 8 + f) * 64 + lane];
      acc[f] = __builtin_amdgcn_mfma_f32_16x16x32_bf16(a, bf, acc[f], 0, 0, 0);
    }
  }
  const int col_lo = lane & 15;
  const int rq = (lane >> 4) * 4;
#pragma unroll
  for (int f = 0; f < 8; ++f) {
    int col = f * 16 + col_lo;
    float bias = b[col];
#pragma unroll
    for (int r = 0; r < 4; ++r) {
      int row = row0 + rbase + rq + r;
      if (row < nrows) {
        float vv = fmaxf(acc[f][r] + bias, 0.f);
        h[(size_t)row * 128 + col] = f2bf(vv);
      }
    }
  }
}

// ---------------- layer2 projection: p = h@Wl2 (row-major [n][64]) ------------------
__global__ __launch_bounds__(256) void k_proj2(const ushort* __restrict__ hb,
                                               const ushort* __restrict__ Wp,
                                               ushort* __restrict__ p, int nrows) {
  __shared__ __align__(16) ushort As[64 * 128];  // 16KB
  const int tid = threadIdx.x;
  const int row0 = blockIdx.x * 64;
#pragma unroll
  for (int i = 0; i < 4; ++i) {
    int c = tid + i * 256;
    int r = c >> 4;
    int c16 = c & 15;
    int grow = row0 + r;
    short8v v = {0, 0, 0, 0, 0, 0, 0, 0};
    if (grow < nrows) v = *reinterpret_cast<const short8v*>(hb + (size_t)grow * 128 + c16 * 8);
    int dbyte = r * 256 + ((c16 * 16) ^ ((r & 7) << 4));
    *reinterpret_cast<short8v*>(reinterpret_cast<char*>(As) + dbyte) = v;
  }
  __syncthreads();
  const int lane = tid & 63;
  const int rbase = (tid >> 6) * 16;
  const int arow = rbase + (lane & 15);
  const int axor = (arow & 7) << 4;
  const short8v* Wp8 = reinterpret_cast<const short8v*>(Wp);
  float4v acc[3];
#pragma unroll
  for (int f = 0; f < 3; ++f) acc[f] = {0.f, 0.f, 0.f, 0.f};
#pragma unroll
  for (int ks = 0; ks < 4; ++ks) {
    int abyte = arow * 256 + ((ks * 64 + (lane >> 4) * 16) ^ axor);
    short8v a = *reinterpret_cast<const short8v*>(reinterpret_cast<const char*>(As) + abyte);
#pragma unroll
    for (int f = 0; f < 3; ++f) {
      short8v bf = Wp8[(ks * 3 + f) * 64 + lane];
      acc[f] = __builtin_amdgcn_mfma_f32_16x16x32_bf16(a, bf, acc[f], 0, 0, 0);
    }
  }
  const int col_lo = lane & 15;
  const int rq = (lane >> 4) * 4;
#pragma unroll
  for (int f = 0; f < 3; ++f) {
    int col = f * 16 + col_lo;
#pragma unroll
    for (int r = 0; r < 4; ++r) {
      int row = row0 + rbase + rq + r;
      if (row < nrows) p[(size_t)row * 64 + col] = f2bf(acc[f][r]);
    }
  }
  // zero cols 48..63
#pragma unroll
  for (int r = 0; r < 4; ++r) {
    int row = row0 + rbase + rq + r;
    if (row < nrows) p[(size_t)row * 64 + 48 + col_lo] = 0;
  }
}

// ---------------- layer2 root: out = h@Wr2 + m + b2 (fp32 out, 40 cols) --------------
__global__ __launch_bounds__(256) void k_root2(const ushort* __restrict__ hb,
                                               const ushort* __restrict__ Wp,
                                               const float* __restrict__ b,
                                               const float* __restrict__ m,
                                               float* __restrict__ out, int nrows) {
  __shared__ __align__(16) ushort As[64 * 128];
  const int tid = threadIdx.x;
  const int row0 = blockIdx.x * 64;
#pragma unroll
  for (int i = 0; i < 4; ++i) {
    int c = tid + i * 256;
    int r = c >> 4;
    int c16 = c & 15;
    int grow = row0 + r;
    short8v v = {0, 0, 0, 0, 0, 0, 0, 0};
    if (grow < nrows) v = *reinterpret_cast<const short8v*>(hb + (size_t)grow * 128 + c16 * 8);
    int dbyte = r * 256 + ((c16 * 16) ^ ((r & 7) << 4));
    *reinterpret_cast<short8v*>(reinterpret_cast<char*>(As) + dbyte) = v;
  }
  __syncthreads();
  const int lane = tid & 63;
  const int rbase = (tid >> 6) * 16;
  const int arow = rbase + (lane & 15);
  const int axor = (arow & 7) << 4;
  const short8v* Wp8 = reinterpret_cast<const short8v*>(Wp);
  float4v acc[3];
#pragma unroll
  for (int f = 0; f < 3; ++f) acc[f] = {0.f, 0.f, 0.f, 0.f};
#pragma unroll
  for (int ks = 0; ks < 4; ++ks) {
    int abyte = arow * 256 + ((ks * 64 + (lane >> 4) * 16) ^ axor);
    short8v a = *reinterpret_cast<const short8v*>(reinterpret_cast<const char*>(As) + abyte);
#pragma unroll
    for (int f = 0; f < 3; ++f) {
      short8v bf = Wp8[(ks * 3 + f) * 64 + lane];
      acc[f] = __builtin_amdgcn_mfma_f32_16x16x32_bf16(a, bf, acc[f], 0, 0, 0);
    }
  }
  const int col_lo = lane & 15;
  const int rq = (lane >> 4) * 4;
#pragma unroll
  for (int f = 0; f < 3; ++f) {
    int col = f * 16 + col_lo;
    if (col < CLSN) {
      float bias = b[col];
#pragma unroll
      for (int r = 0; r < 4; ++r) {
        int row = row0 + rbase + rq + r;
        if (row < nrows)
          out[(size_t)row * CLSN + col] = acc[f][r] + bias + m[(size_t)row * 64 + col];
      }
    }
  }
}

extern "C" void kernel_launch(void* const* d_in, const int* in_sizes, int n_in,
                              void* d_out, int out_size, void* d_ws, size_t ws_size,
                              hipStream_t stream) {
  const float* x = (const float*)d_in[0];
  const int* ei = (const int*)d_in[1];
  const float* Wl1 = (const float*)d_in[2];
  const float* Wr1 = (const float*)d_in[3];
  const float* b1 = (const float*)d_in[4];
  const float* Wl2 = (const float*)d_in[5];
  const float* Wr2 = (const float*)d_in[6];
  const float* b2 = (const float*)d_in[7];
  float* out = (float*)d_out;

  const int n = in_sizes[0] / F;
  const int E = in_sizes[1] / 2;
  const int* src = ei;
  const int* dst = ei + E;

  const int nfine = (n + 511) >> 9;  // 196

  size_t off = 0;
  auto alloc = [&](size_t bytes) {
    size_t cur = off;
    off = (off + bytes + 255) & ~(size_t)255;
    return cur;
  };
  char* w = (char*)d_ws;
  int* offsets = (int*)(w + alloc((size_t)(n + 1) * 4));
  int* srcs = (int*)(w + alloc((size_t)E * 4));
  int* fcur = (int*)(w + alloc(NFINE_MAX * 4));
  int* fbase = (int*)(w + alloc((NFINE_MAX + 1) * 4));
  ushort* xb = (ushort*)(w + alloc((size_t)n * F * 2));
  ushort* hb = (ushort*)(w + alloc((size_t)n * F * 2));
  ushort* meanb = (ushort*)(w + alloc((size_t)n * F * 2));
  ushort* Wp1 = (ushort*)(w + alloc(32768 * 2));
  ushort* Wp2l = (ushort*)(w + alloc(6144 * 2));
  ushort* Wp2r = (ushort*)(w + alloc(6144 * 2));
  (void)ws_size;
  // aliases: pairs (CSR build) and p64 (layer2 projection) live in meanb's region
  // (dead at those times); m64 (fp32, N*64) lives in xb's region (dead after mfma1);
  // xq8 (int8 gather table, N*128 = half of hb region) is dead before mfma1 writes h.
  uint* pairs = (uint*)meanb;
  ushort* p64 = meanb;                    // N*64 bf16 = half of meanb region
  float* m64 = (float*)xb;                // N*64 f32 = exactly xb region size
  unsigned char* xq8 = (unsigned char*)hb;  // N*128 int8 = half of hb region

  // casts / weight packing
  k_cast<<<(n * 32 + 255) / 256, 256, 0, stream>>>(x, xb, xq8, n * 32);
  k_pack_w1<<<16, 256, 0, stream>>>(Wl1, Wr1, Wp1);
  k_pack_w2pair<<<6, 256, 0, stream>>>(Wl2, Wr2, Wp2l, Wp2r);

  // binned CSR build (one-pass tiled radix partition)
  k_init_fcur<<<1, 256, 0, stream>>>(fcur, nfine);
  k_partition<<<(E + TILE - 1) / TILE, 256, 0, stream>>>(src, dst, fcur, pairs, E);
  k_scan_fine<<<1, 256, 0, stream>>>(fcur, fbase, nfine, E);
  k_local_scatter<<<nfine, 256, 0, stream>>>(pairs, fcur, fbase, offsets, srcs, n, E);

  // layer 1: mean(x) via int8 gather -> h = relu([mean|x]@W1 + b1)
  k_agg_x<<<(n + 15) / 16, 256, 0, stream>>>(xq8, offsets, srcs, meanb, n);
  k_mfma1<<<(n + 63) / 64, 256, 0, stream>>>(meanb, xb, Wp1, b1, hb, n);

  // layer 2 (projection-first): p = h@Wl2; m = mean(p); out = h@Wr2 + m + b2
  k_proj2<<<(n + 63) / 64, 256, 0, stream>>>(hb, Wp2l, p64, n);
  k_agg_p<<<(n + 31) / 32, 256, 0, stream>>>(p64, offsets, srcs, m64, n);
  k_root2<<<(n + 63) / 64, 256, 0, stream>>>(hb, Wp2r, b2, m64, out, n);
}